// Round 4
// baseline (220.948 us; speedup 1.0000x reference)
//
#include <hip/hip_runtime.h>
#include <hip/hip_bf16.h>
#include <math.h>

#define BATCH 2
#define SEQ   2048
#define EMB   1024
#define NH    16
#define HD    64
#define K_DIM 1024
#define QSCALE 0.18033688011f   /* 0.125 * log2(e): folded into q projection */

typedef __hip_bfloat16 bf16;
typedef __attribute__((ext_vector_type(8))) short short8;
typedef __attribute__((ext_vector_type(4))) short short4v;
typedef __attribute__((ext_vector_type(4))) float f32x4;
typedef __attribute__((ext_vector_type(2))) unsigned int uint2v;

// gfx950 HW packed f32->bf16 (RTNE)
__device__ __forceinline__ unsigned cvt_pk_bf16(float a, float b) {
    unsigned r;
    asm("v_cvt_pk_bf16_f32 %0, %1, %2" : "=v"(r) : "v"(a), "v"(b));
    return r;
}
__device__ __forceinline__ void st_bf2(bf16* p0, bf16* p1, float a, float b) {
    unsigned pk = cvt_pk_bf16(a, b);
    *(short*)p0 = (short)(pk & 0xffff);
    *(short*)p1 = (short)(pk >> 16);
}

// async global->LDS, 16B per lane; LDS dest = wave-uniform base + lane*16
__device__ __forceinline__ void gld_lds16(const bf16* g, bf16* l) {
    __builtin_amdgcn_global_load_lds(
        (const __attribute__((address_space(1))) unsigned int*)g,
        (__attribute__((address_space(3))) unsigned int*)l, 16, 0, 0);
}

// ---------------------------------------------------------------------------
// Convert x and Wq|Wk|Wv|Wo to bf16 into contiguous dst [xb | wq wk wv wo].
// ---------------------------------------------------------------------------
__global__ __launch_bounds__(256)
void cvt_pack(const float* __restrict__ x,  const float* __restrict__ wq,
              const float* __restrict__ wk, const float* __restrict__ wv,
              const float* __restrict__ wo, short* __restrict__ dst)
{
    size_t gid = ((size_t)blockIdx.x * 256 + threadIdx.x) * 4;
    int seg = (int)(gid >> 20);
    const float* src; size_t off;
    if (seg < 4)       { src = x;  off = gid; }
    else if (seg == 4) { src = wq; off = gid - ((size_t)4 << 20); }
    else if (seg == 5) { src = wk; off = gid - ((size_t)5 << 20); }
    else if (seg == 6) { src = wv; off = gid - ((size_t)6 << 20); }
    else               { src = wo; off = gid - ((size_t)7 << 20); }
    f32x4 v = *(const f32x4*)(src + off);
    uint2v pk = { cvt_pk_bf16(v[0], v[1]), cvt_pk_bf16(v[2], v[3]) };
    *(uint2v*)(dst + gid) = pk;
}

// ---------------------------------------------------------------------------
// Fused QKV GEMM (unchanged, verified). Masked K/V rows zeroed in epilogue.
// ---------------------------------------------------------------------------
__global__ __launch_bounds__(256)
void gemm_qkv2(const bf16* __restrict__ xb, const bf16* __restrict__ wb,
               const float* __restrict__ bq, const float* __restrict__ bk_,
               const float* __restrict__ bv_, const int* __restrict__ mask,
               bf16* __restrict__ q, bf16* __restrict__ kt, bf16* __restrict__ vt)
{
    __shared__ __align__(16) bf16 As[128 * 32];
    __shared__ __align__(16) bf16 Bs[128 * 32];

    const int tid  = threadIdx.x;
    const int proj = blockIdx.x >> 3;
    const int n0   = (blockIdx.x & 7) * 128;
    const int m0   = blockIdx.y * 128;
    const bf16* W  = wb + ((size_t)proj << 20);
    const float* bias = (proj == 0) ? bq : (proj == 1) ? bk_ : bv_;

    const int wave = tid >> 6, lane = tid & 63;
    const int wm = wave >> 1, wn = wave & 1;
    const int lr = lane & 15, lg = lane >> 4;
    const int srow = lane >> 2;
    const int scol = (lane & 3) * 8;

    f32x4 acc[4][4];
    for (int mi = 0; mi < 4; ++mi)
        for (int ni = 0; ni < 4; ++ni) acc[mi][ni] = (f32x4){0.f,0.f,0.f,0.f};

    for (int k0 = 0; k0 < K_DIM; k0 += 32) {
        for (int i = 0; i < 2; ++i) {
            int rb = (wave * 2 + i) * 16;
            gld_lds16(&xb[(size_t)(m0 + rb + srow) * K_DIM + k0 + scol], &As[rb * 32]);
            gld_lds16(&W [(size_t)(n0 + rb + srow) * K_DIM + k0 + scol], &Bs[rb * 32]);
        }
        __syncthreads();
        short8 af[4], bf_[4];
        for (int mi = 0; mi < 4; ++mi)
            af[mi]  = *(const short8*)&As[(wm * 64 + mi * 16 + lr) * 32 + lg * 8];
        for (int ni = 0; ni < 4; ++ni)
            bf_[ni] = *(const short8*)&Bs[(wn * 64 + ni * 16 + lr) * 32 + lg * 8];
        for (int mi = 0; mi < 4; ++mi)
            for (int ni = 0; ni < 4; ++ni)
                acc[mi][ni] = __builtin_amdgcn_mfma_f32_16x16x32_bf16(
                    af[mi], bf_[ni], acc[mi][ni], 0, 0, 0);
        __syncthreads();
    }

    int msk[4][4];
    if (proj != 0) {
        for (int mi = 0; mi < 4; ++mi) {
            int mbase = m0 + wm * 64 + mi * 16 + lg * 4;
            int b = mbase >> 11, s0 = mbase & 2047;
            int4 mm = *(const int4*)&mask[(size_t)b * SEQ + s0];
            msk[mi][0] = mm.x; msk[mi][1] = mm.y; msk[mi][2] = mm.z; msk[mi][3] = mm.w;
        }
    }

    for (int mi = 0; mi < 4; ++mi)
        for (int ni = 0; ni < 4; ++ni) {
            int n = n0 + wn * 64 + ni * 16 + lr;
            float bvv = bias[n];
            int h = n >> 6, d = n & 63;
            int mbase = m0 + wm * 64 + mi * 16 + lg * 4;
            int b = mbase >> 11, s0 = mbase & 2047;
            float v0 = acc[mi][ni][0] + bvv, v1 = acc[mi][ni][1] + bvv;
            float v2 = acc[mi][ni][2] + bvv, v3 = acc[mi][ni][3] + bvv;
            if (proj == 0) {
                bf16* p = q + ((((size_t)b * NH) + h) * SEQ + s0) * HD + d;
                st_bf2(p,          p + HD,     v0 * QSCALE, v1 * QSCALE);
                st_bf2(p + 2 * HD, p + 3 * HD, v2 * QSCALE, v3 * QSCALE);
            } else if (proj == 1) {
                if (msk[mi][0]) v0 = 0.f;
                if (msk[mi][1]) v1 = 0.f;
                if (msk[mi][2]) v2 = 0.f;
                if (msk[mi][3]) v3 = 0.f;
                bf16* p = kt + ((((size_t)b * NH) + h) * SEQ + s0) * HD + d;
                st_bf2(p,          p + HD,     v0, v1);
                st_bf2(p + 2 * HD, p + 3 * HD, v2, v3);
            } else {
                if (msk[mi][0]) v0 = 0.f;
                if (msk[mi][1]) v1 = 0.f;
                if (msk[mi][2]) v2 = 0.f;
                if (msk[mi][3]) v3 = 0.f;
                uint2v pk = { cvt_pk_bf16(v0, v1), cvt_pk_bf16(v2, v3) };
                *(uint2v*)((short*)vt + ((((size_t)b * NH) + h) * HD + d) * SEQ + s0) = pk;
            }
        }
}

// ---------------------------------------------------------------------------
// Out projection (unchanged, verified)
// ---------------------------------------------------------------------------
__global__ __launch_bounds__(256)
void gemm_out2(const bf16* __restrict__ A, const bf16* __restrict__ W,
               const float* __restrict__ bias, float* __restrict__ C)
{
    __shared__ __align__(16) bf16 As[128 * 32];
    __shared__ __align__(16) bf16 Bs[64 * 32];

    const int tid = threadIdx.x;
    const int n0  = blockIdx.x * 64;
    const int m0  = blockIdx.y * 128;
    const int wave = tid >> 6, lane = tid & 63;
    const int wm = wave >> 1, wn = wave & 1;
    const int lr = lane & 15, lg = lane >> 4;
    const int srow = lane >> 2, scol = (lane & 3) * 8;

    f32x4 acc[4][2];
    for (int mi = 0; mi < 4; ++mi)
        for (int ni = 0; ni < 2; ++ni) acc[mi][ni] = (f32x4){0.f,0.f,0.f,0.f};

    for (int k0 = 0; k0 < K_DIM; k0 += 32) {
        for (int i = 0; i < 2; ++i) {
            int rb = (wave * 2 + i) * 16;
            gld_lds16(&A[(size_t)(m0 + rb + srow) * K_DIM + k0 + scol], &As[rb * 32]);
        }
        {
            int rb = wave * 16;
            gld_lds16(&W[(size_t)(n0 + rb + srow) * K_DIM + k0 + scol], &Bs[rb * 32]);
        }
        __syncthreads();
        short8 af[4], bf_[2];
        for (int mi = 0; mi < 4; ++mi)
            af[mi]  = *(const short8*)&As[(wm * 64 + mi * 16 + lr) * 32 + lg * 8];
        for (int ni = 0; ni < 2; ++ni)
            bf_[ni] = *(const short8*)&Bs[(wn * 32 + ni * 16 + lr) * 32 + lg * 8];
        for (int mi = 0; mi < 4; ++mi)
            for (int ni = 0; ni < 2; ++ni)
                acc[mi][ni] = __builtin_amdgcn_mfma_f32_16x16x32_bf16(
                    af[mi], bf_[ni], acc[mi][ni], 0, 0, 0);
        __syncthreads();
    }

    for (int mi = 0; mi < 4; ++mi)
        for (int ni = 0; ni < 2; ++ni) {
            int n = n0 + wn * 32 + ni * 16 + lr;
            float bvv = bias[n];
            int mbase = m0 + wm * 64 + mi * 16 + lg * 4;
            for (int r = 0; r < 4; ++r)
                C[(size_t)(mbase + r) * EMB + n] = acc[mi][ni][r] + bvv;
        }
}

// ---------------------------------------------------------------------------
// Flash attention v9: BISECTION STEP from verified v6 (50us).
// EXACTLY ONE change vs v6: V^T staging removed -- V fragments are read
// directly from global (address = composition of v6's stage+frag-read
// indices, element-identical data). Everything else is v6 VERBATIM:
//   - both in-loop __syncthreads(), K staging + register prefetch pipeline
//   - Q staged in Pb[0], sred nmask, P layout/write/read, epilogue, LDS map
//   - grid dim3(SEQ/128, NH, BATCH), 512 threads, no blockIdx swizzle
// Purpose: v7/v8 (K+V direct + barrier removal together) fail with a
// nondeterministic-magnitude error; this isolates the V-direct read as the
// single variable. VtB region stays allocated (Osc overlays Ks+Vt in the
// epilogue exactly as v6).
// ---------------------------------------------------------------------------
__global__ __launch_bounds__(512, 4)
void attn_flash9(const bf16* __restrict__ q, const bf16* __restrict__ k,
                 const bf16* __restrict__ vt, const int* __restrict__ mask,
                 bf16* __restrict__ attn)
{
    __shared__ __align__(16) char smem[73728];
    bf16* PbB = (bf16*)smem;              // [2][128][72]  (g0 doubles as Q stage)
    bf16* KsB = (bf16*)(smem + 36864);    // [2][64][72]
    __shared__ float sred[8];

    const int q0   = blockIdx.x * 128;
    const int h    = blockIdx.y;
    const int b    = blockIdx.z;
    const int tid  = threadIdx.x;
    const int lane = tid & 63;
    const int wave = tid >> 6;            // 0..7
    const int g    = wave >> 2;           // key group 0/1
    const int qoff = (wave & 3) * 32;     // this wave's 32 query rows
    const int lr   = lane & 15;
    const int lg   = lane >> 4;

    const size_t bh  = ((size_t)b * NH + h) * SEQ;
    const size_t bhd = ((size_t)b * NH + h) * HD;

    // masked-key count for batch b
    int4 mm = *(const int4*)&mask[(size_t)b * SEQ + tid * 4];
    int cnt = (mm.x != 0) + (mm.y != 0) + (mm.z != 0) + (mm.w != 0);
    for (int off = 32; off; off >>= 1) cnt += __shfl_xor(cnt, off);
    if (lane == 0) sred[wave] = (float)cnt;

    // stage Q tile into Pb[0] region (8192 elems, 16/thread)
    for (int i = 0; i < 2; ++i) {
        int e = tid + i * 512;
        int r = e >> 3, c = (e & 7) * 8;
        *(short8*)&PbB[r * 72 + c] = *(const short8*)&q[(bh + q0 + r) * HD + c];
    }
    __syncthreads();

    const float nmask = sred[0] + sred[1] + sred[2] + sred[3] +
                        sred[4] + sred[5] + sred[6] + sred[7];

    // Q as B-operand frags for this wave's 32 queries (2 x 16)
    short8 bq_[2][2];
    for (int mi = 0; mi < 2; ++mi) {
        bq_[mi][0] = *(const short8*)&PbB[(qoff + mi * 16 + lr) * 72 + lg * 8];
        bq_[mi][1] = *(const short8*)&PbB[(qoff + mi * 16 + lr) * 72 + 32 + lg * 8];
    }

    short8 ones;
    for (int j = 0; j < 8; ++j) ones[j] = (short)0x3F80;   // bf16 1.0

    f32x4 o[2][4], lacc[2];
    for (int mi = 0; mi < 2; ++mi) {
        lacc[mi] = (f32x4){0.f,0.f,0.f,0.f};
        for (int db = 0; db < 4; ++db) o[mi][db] = (f32x4){0.f,0.f,0.f,0.f};
    }

    // staging: 512 threads x 2 chunks cover both groups' K tiles (V removed)
    short8 pk_[2];
    auto ld = [&](int it) {
        int k0 = it * 64;
        for (int i = 0; i < 2; ++i) {
            int e = tid + i * 512;
            int gg = e >> 9, r = (e >> 3) & 63, c = (e & 7) * 8;
            int kk = k0 + gg * 1024;
            pk_[i] = *(const short8*)&k[(bh + kk + r) * HD + c];
        }
    };
    ld(0);

    for (int it = 0; it < 16; ++it) {
        for (int i = 0; i < 2; ++i) {
            int e = tid + i * 512;
            int gg = e >> 9, r = (e >> 3) & 63, c = (e & 7) * 8;
            *(short8*)&KsB[(gg * 64 + r) * 72 + c] = pk_[i];
        }
        __syncthreads();
        if (it + 1 < 16) ld(it + 1);

        const int kk = g * 1024 + it * 64;   // this group's 64-key tile base

        // S^T = K Q^T over this group's 64-key tile
        for (int cb = 0; cb < 4; ++cb) {
            short8 a0 = *(const short8*)&KsB[(g * 64 + cb * 16 + lr) * 72 + lg * 8];
            short8 a1 = *(const short8*)&KsB[(g * 64 + cb * 16 + lr) * 72 + 32 + lg * 8];
            for (int mi = 0; mi < 2; ++mi) {
                f32x4 cc = (f32x4){0.f,0.f,0.f,0.f};
                cc = __builtin_amdgcn_mfma_f32_16x16x32_bf16(a0, bq_[mi][0], cc, 0, 0, 0);
                cc = __builtin_amdgcn_mfma_f32_16x16x32_bf16(a1, bq_[mi][1], cc, 0, 0, 0);
                uint2v pkv = {
                    cvt_pk_bf16(__builtin_amdgcn_exp2f(cc[0]),
                                __builtin_amdgcn_exp2f(cc[1])),
                    cvt_pk_bf16(__builtin_amdgcn_exp2f(cc[2]),
                                __builtin_amdgcn_exp2f(cc[3])) };
                *(uint2v*)&PbB[(g * 128 + qoff + mi * 16 + lr) * 72 + cb * 16 + lg * 4] = pkv;
            }
        }

        // O += P V ; l += P 1   (wave-private P rows: no barrier needed)
        short8 ap[2][2];
        for (int mi = 0; mi < 2; ++mi) {
            ap[mi][0] = *(const short8*)&PbB[(g * 128 + qoff + mi * 16 + lr) * 72 + lg * 8];
            ap[mi][1] = *(const short8*)&PbB[(g * 128 + qoff + mi * 16 + lr) * 72 + 32 + lg * 8];
        }
        for (int db = 0; db < 4; ++db) {
            // ONLY CHANGE vs v6: V^T frags straight from global (rows are
            // full 128B lines; same elements v6 staged into VtB)
            const bf16* vr = &vt[(bhd + db * 16 + lr) * SEQ + kk + lg * 8];
            short8 bv0 = *(const short8*)vr;
            short8 bv1 = *(const short8*)(vr + 32);
            for (int mi = 0; mi < 2; ++mi) {
                o[mi][db] = __builtin_amdgcn_mfma_f32_16x16x32_bf16(ap[mi][0], bv0, o[mi][db], 0, 0, 0);
                o[mi][db] = __builtin_amdgcn_mfma_f32_16x16x32_bf16(ap[mi][1], bv1, o[mi][db], 0, 0, 0);
            }
        }
        for (int mi = 0; mi < 2; ++mi) {
            lacc[mi] = __builtin_amdgcn_mfma_f32_16x16x32_bf16(ap[mi][0], ones, lacc[mi], 0, 0, 0);
            lacc[mi] = __builtin_amdgcn_mfma_f32_16x16x32_bf16(ap[mi][1], ones, lacc[mi], 0, 0, 0);
        }
        __syncthreads();
    }

    // combine the two key-halves through LDS scratch, normalize, store
    float* Osc  = (float*)(smem + 36864);  // 32 KB over Ks+Vt region
    float* larr = (float*)smem;            // over Pb[0]
    if (g == 1) {
        for (int mi = 0; mi < 2; ++mi) {
            for (int db = 0; db < 4; ++db)
                for (int r = 0; r < 4; ++r)
                    Osc[(qoff + mi * 16 + lg * 4 + r) * 64 + db * 16 + lr] = o[mi][db][r];
            if (lr == 0)
                for (int r = 0; r < 4; ++r)
                    larr[qoff + mi * 16 + lg * 4 + r] = lacc[mi][r];
        }
    }
    __syncthreads();
    if (g == 0) {
        for (int mi = 0; mi < 2; ++mi) {
            int qr = qoff + mi * 16 + lg * 4;
            f32x4 linv;
            for (int r = 0; r < 4; ++r)
                linv[r] = 1.f / (lacc[mi][r] + larr[qr + r] - nmask);
            for (int db = 0; db < 4; ++db) {
                int col = h * HD + db * 16 + lr;
                float vv[4];
                for (int r = 0; r < 4; ++r)
                    vv[r] = (o[mi][db][r] + Osc[(qr + r) * 64 + db * 16 + lr]) * linv[r];
                bf16* p = attn + ((size_t)b * SEQ + q0 + qr) * EMB + col;
                st_bf2(p,           p + EMB,     vv[0], vv[1]);
                st_bf2(p + 2 * EMB, p + 3 * EMB, vv[2], vv[3]);
            }
        }
    }
}

// ---------------------------------------------------------------------------
extern "C" void kernel_launch(void* const* d_in, const int* in_sizes, int n_in,
                              void* d_out, int out_size, void* d_ws, size_t ws_size,
                              hipStream_t stream)
{
    const float* x    = (const float*)d_in[0];
    const int*   mask = (const int*)d_in[1];
    const float* Wq   = (const float*)d_in[2];
    const float* bq   = (const float*)d_in[3];
    const float* Wk   = (const float*)d_in[4];
    const float* bk   = (const float*)d_in[5];
    const float* Wv   = (const float*)d_in[6];
    const float* bv   = (const float*)d_in[7];
    const float* Wo   = (const float*)d_in[8];
    const float* bo   = (const float*)d_in[9];
    float* out = (float*)d_out;

    const size_t TENS = (size_t)BATCH * SEQ * EMB;   // 2^22
    bf16* q    = (bf16*)d_ws;
    bf16* kt   = q    + TENS;
    bf16* vt   = kt   + TENS;
    bf16* attn = vt   + TENS;
    bf16* xb   = attn + TENS;
    bf16* wb   = xb   + TENS;     // 4 x 2^20 = TENS

    cvt_pack<<<8192, 256, 0, stream>>>(x, Wq, Wk, Wv, Wo, (short*)xb);

    gemm_qkv2<<<dim3(24, 32), 256, 0, stream>>>(xb, wb, bq, bk, bv, mask, q, kt, vt);

    attn_flash9<<<dim3(SEQ / 128, NH, BATCH), 512, 0, stream>>>(q, kt, vt, mask, attn);

    gemm_out2<<<dim3(16, 32), 256, 0, stream>>>(attn, wb + ((size_t)3 << 20), bo, out);
}

// Round 6
// 189.567 us; speedup vs baseline: 1.1655x; 1.1655x over previous
//
#include <hip/hip_runtime.h>
#include <hip/hip_bf16.h>
#include <math.h>

#define BATCH 2
#define SEQ   2048
#define EMB   1024
#define NH    16
#define HD    64
#define K_DIM 1024
#define QSCALE 0.18033688011f   /* 0.125 * log2(e): folded into q projection */

typedef __hip_bfloat16 bf16;
typedef __attribute__((ext_vector_type(8))) short short8;
typedef __attribute__((ext_vector_type(4))) short short4v;
typedef __attribute__((ext_vector_type(4))) float f32x4;
typedef __attribute__((ext_vector_type(2))) unsigned int uint2v;

// gfx950 HW packed f32->bf16 (RTNE)
__device__ __forceinline__ unsigned cvt_pk_bf16(float a, float b) {
    unsigned r;
    asm("v_cvt_pk_bf16_f32 %0, %1, %2" : "=v"(r) : "v"(a), "v"(b));
    return r;
}
__device__ __forceinline__ void st_bf2(bf16* p0, bf16* p1, float a, float b) {
    unsigned pk = cvt_pk_bf16(a, b);
    *(short*)p0 = (short)(pk & 0xffff);
    *(short*)p1 = (short)(pk >> 16);
}

// async global->LDS, 16B per lane; LDS dest = wave-uniform base + lane*16
__device__ __forceinline__ void gld_lds16(const bf16* g, bf16* l) {
    __builtin_amdgcn_global_load_lds(
        (const __attribute__((address_space(1))) unsigned int*)g,
        (__attribute__((address_space(3))) unsigned int*)l, 16, 0, 0);
}

// ---------------------------------------------------------------------------
// Convert x and Wq|Wk|Wv|Wo to bf16 into contiguous dst [xb | wq wk wv wo].
// ---------------------------------------------------------------------------
__global__ __launch_bounds__(256)
void cvt_pack(const float* __restrict__ x,  const float* __restrict__ wq,
              const float* __restrict__ wk, const float* __restrict__ wv,
              const float* __restrict__ wo, short* __restrict__ dst)
{
    size_t gid = ((size_t)blockIdx.x * 256 + threadIdx.x) * 4;
    int seg = (int)(gid >> 20);
    const float* src; size_t off;
    if (seg < 4)       { src = x;  off = gid; }
    else if (seg == 4) { src = wq; off = gid - ((size_t)4 << 20); }
    else if (seg == 5) { src = wk; off = gid - ((size_t)5 << 20); }
    else if (seg == 6) { src = wv; off = gid - ((size_t)6 << 20); }
    else               { src = wo; off = gid - ((size_t)7 << 20); }
    f32x4 v = *(const f32x4*)(src + off);
    uint2v pk = { cvt_pk_bf16(v[0], v[1]), cvt_pk_bf16(v[2], v[3]) };
    *(uint2v*)(dst + gid) = pk;
}

// ---------------------------------------------------------------------------
// Fused QKV GEMM (unchanged, verified). Masked K/V rows zeroed in epilogue.
// ---------------------------------------------------------------------------
__global__ __launch_bounds__(256)
void gemm_qkv2(const bf16* __restrict__ xb, const bf16* __restrict__ wb,
               const float* __restrict__ bq, const float* __restrict__ bk_,
               const float* __restrict__ bv_, const int* __restrict__ mask,
               bf16* __restrict__ q, bf16* __restrict__ kt, bf16* __restrict__ vt)
{
    __shared__ __align__(16) bf16 As[128 * 32];
    __shared__ __align__(16) bf16 Bs[128 * 32];

    const int tid  = threadIdx.x;
    const int proj = blockIdx.x >> 3;
    const int n0   = (blockIdx.x & 7) * 128;
    const int m0   = blockIdx.y * 128;
    const bf16* W  = wb + ((size_t)proj << 20);
    const float* bias = (proj == 0) ? bq : (proj == 1) ? bk_ : bv_;

    const int wave = tid >> 6, lane = tid & 63;
    const int wm = wave >> 1, wn = wave & 1;
    const int lr = lane & 15, lg = lane >> 4;
    const int srow = lane >> 2;
    const int scol = (lane & 3) * 8;

    f32x4 acc[4][4];
    for (int mi = 0; mi < 4; ++mi)
        for (int ni = 0; ni < 4; ++ni) acc[mi][ni] = (f32x4){0.f,0.f,0.f,0.f};

    for (int k0 = 0; k0 < K_DIM; k0 += 32) {
        for (int i = 0; i < 2; ++i) {
            int rb = (wave * 2 + i) * 16;
            gld_lds16(&xb[(size_t)(m0 + rb + srow) * K_DIM + k0 + scol], &As[rb * 32]);
            gld_lds16(&W [(size_t)(n0 + rb + srow) * K_DIM + k0 + scol], &Bs[rb * 32]);
        }
        __syncthreads();
        short8 af[4], bf_[4];
        for (int mi = 0; mi < 4; ++mi)
            af[mi]  = *(const short8*)&As[(wm * 64 + mi * 16 + lr) * 32 + lg * 8];
        for (int ni = 0; ni < 4; ++ni)
            bf_[ni] = *(const short8*)&Bs[(wn * 64 + ni * 16 + lr) * 32 + lg * 8];
        for (int mi = 0; mi < 4; ++mi)
            for (int ni = 0; ni < 4; ++ni)
                acc[mi][ni] = __builtin_amdgcn_mfma_f32_16x16x32_bf16(
                    af[mi], bf_[ni], acc[mi][ni], 0, 0, 0);
        __syncthreads();
    }

    int msk[4][4];
    if (proj != 0) {
        for (int mi = 0; mi < 4; ++mi) {
            int mbase = m0 + wm * 64 + mi * 16 + lg * 4;
            int b = mbase >> 11, s0 = mbase & 2047;
            int4 mm = *(const int4*)&mask[(size_t)b * SEQ + s0];
            msk[mi][0] = mm.x; msk[mi][1] = mm.y; msk[mi][2] = mm.z; msk[mi][3] = mm.w;
        }
    }

    for (int mi = 0; mi < 4; ++mi)
        for (int ni = 0; ni < 4; ++ni) {
            int n = n0 + wn * 64 + ni * 16 + lr;
            float bvv = bias[n];
            int h = n >> 6, d = n & 63;
            int mbase = m0 + wm * 64 + mi * 16 + lg * 4;
            int b = mbase >> 11, s0 = mbase & 2047;
            float v0 = acc[mi][ni][0] + bvv, v1 = acc[mi][ni][1] + bvv;
            float v2 = acc[mi][ni][2] + bvv, v3 = acc[mi][ni][3] + bvv;
            if (proj == 0) {
                bf16* p = q + ((((size_t)b * NH) + h) * SEQ + s0) * HD + d;
                st_bf2(p,          p + HD,     v0 * QSCALE, v1 * QSCALE);
                st_bf2(p + 2 * HD, p + 3 * HD, v2 * QSCALE, v3 * QSCALE);
            } else if (proj == 1) {
                if (msk[mi][0]) v0 = 0.f;
                if (msk[mi][1]) v1 = 0.f;
                if (msk[mi][2]) v2 = 0.f;
                if (msk[mi][3]) v3 = 0.f;
                bf16* p = kt + ((((size_t)b * NH) + h) * SEQ + s0) * HD + d;
                st_bf2(p,          p + HD,     v0, v1);
                st_bf2(p + 2 * HD, p + 3 * HD, v2, v3);
            } else {
                if (msk[mi][0]) v0 = 0.f;
                if (msk[mi][1]) v1 = 0.f;
                if (msk[mi][2]) v2 = 0.f;
                if (msk[mi][3]) v3 = 0.f;
                uint2v pk = { cvt_pk_bf16(v0, v1), cvt_pk_bf16(v2, v3) };
                *(uint2v*)((short*)vt + ((((size_t)b * NH) + h) * HD + d) * SEQ + s0) = pk;
            }
        }
}

// ---------------------------------------------------------------------------
// Out projection (unchanged, verified)
// ---------------------------------------------------------------------------
__global__ __launch_bounds__(256)
void gemm_out2(const bf16* __restrict__ A, const bf16* __restrict__ W,
               const float* __restrict__ bias, float* __restrict__ C)
{
    __shared__ __align__(16) bf16 As[128 * 32];
    __shared__ __align__(16) bf16 Bs[64 * 32];

    const int tid = threadIdx.x;
    const int n0  = blockIdx.x * 64;
    const int m0  = blockIdx.y * 128;
    const int wave = tid >> 6, lane = tid & 63;
    const int wm = wave >> 1, wn = wave & 1;
    const int lr = lane & 15, lg = lane >> 4;
    const int srow = lane >> 2, scol = (lane & 3) * 8;

    f32x4 acc[4][2];
    for (int mi = 0; mi < 4; ++mi)
        for (int ni = 0; ni < 2; ++ni) acc[mi][ni] = (f32x4){0.f,0.f,0.f,0.f};

    for (int k0 = 0; k0 < K_DIM; k0 += 32) {
        for (int i = 0; i < 2; ++i) {
            int rb = (wave * 2 + i) * 16;
            gld_lds16(&A[(size_t)(m0 + rb + srow) * K_DIM + k0 + scol], &As[rb * 32]);
        }
        {
            int rb = wave * 16;
            gld_lds16(&W[(size_t)(n0 + rb + srow) * K_DIM + k0 + scol], &Bs[rb * 32]);
        }
        __syncthreads();
        short8 af[4], bf_[2];
        for (int mi = 0; mi < 4; ++mi)
            af[mi]  = *(const short8*)&As[(wm * 64 + mi * 16 + lr) * 32 + lg * 8];
        for (int ni = 0; ni < 2; ++ni)
            bf_[ni] = *(const short8*)&Bs[(wn * 32 + ni * 16 + lr) * 32 + lg * 8];
        for (int mi = 0; mi < 4; ++mi)
            for (int ni = 0; ni < 2; ++ni)
                acc[mi][ni] = __builtin_amdgcn_mfma_f32_16x16x32_bf16(
                    af[mi], bf_[ni], acc[mi][ni], 0, 0, 0);
        __syncthreads();
    }

    for (int mi = 0; mi < 4; ++mi)
        for (int ni = 0; ni < 2; ++ni) {
            int n = n0 + wn * 32 + ni * 16 + lr;
            float bvv = bias[n];
            int mbase = m0 + wm * 64 + mi * 16 + lg * 4;
            for (int r = 0; r < 4; ++r)
                C[(size_t)(mbase + r) * EMB + n] = acc[mi][ni][r] + bvv;
        }
}

// ---------------------------------------------------------------------------
// Flash attention v11 = round-0 verified attn_flash6 (50us green) with ONE
// correctness-neutral change: a bijective XCD-aware relabeling of the 3-D
// block id. Rationale (round-0 counters): latency-bound (MfmaUtil 29 /
// VALUBusy 28 / occ 33, HBM 20%); K/V per (b,h) = 512 KB shared by 16
// blocks, but default dispatch round-robins neighbors across XCDs so each
// XCD streams ~all 32 (b,h) working sets through L3. Mapping 64 consecutive
// logical blocks (= 4 heads = 2 MB K/V) per XCD makes staging loads L2-hits.
// Every in-loop scheduling edit (v7/v8/v10 incl. setprio) broke this kernel;
// this permutation touches NOTHING inside the loop.
// LDS: P[2][128][72] | Ks[2][64][72] | Vt[2][64][72] = 72 KB, 2 blocks/CU.
// ---------------------------------------------------------------------------
__global__ __launch_bounds__(512, 4)
void attn_flash11(const bf16* __restrict__ q, const bf16* __restrict__ k,
                  const bf16* __restrict__ vt, const int* __restrict__ mask,
                  bf16* __restrict__ attn)
{
    __shared__ __align__(16) char smem[73728];
    bf16* PbB = (bf16*)smem;              // [2][128][72]  (g0 doubles as Q stage)
    bf16* KsB = (bf16*)(smem + 36864);    // [2][64][72]
    bf16* VtB = (bf16*)(smem + 55296);    // [2][64][72]
    __shared__ float sred[8];

    // XCD-aware bijective relabeling of (q0, h, b); grid = dim3(16,16,2).
    // bid%8 -> XCD (dispatch round-robins flattened id); each XCD gets 64
    // consecutive swz = 16 q-tiles x 4 heads of one batch (2 MB K/V, L2-fit).
    const int bid = (int)blockIdx.x + ((int)blockIdx.y << 4) + ((int)blockIdx.z << 8);
    const int swz = (bid & 7) * 64 + (bid >> 3);
    const int q0  = (swz & 15) * 128;
    const int h   = (swz >> 4) & 15;
    const int b   = swz >> 8;

    const int tid  = threadIdx.x;
    const int lane = tid & 63;
    const int wave = tid >> 6;            // 0..7
    const int g    = wave >> 2;           // key group 0/1
    const int qoff = (wave & 3) * 32;     // this wave's 32 query rows
    const int lr   = lane & 15;
    const int lg   = lane >> 4;

    const size_t bh  = ((size_t)b * NH + h) * SEQ;
    const size_t bhd = ((size_t)b * NH + h) * HD;

    // masked-key count for batch b
    int4 mm = *(const int4*)&mask[(size_t)b * SEQ + tid * 4];
    int cnt = (mm.x != 0) + (mm.y != 0) + (mm.z != 0) + (mm.w != 0);
    for (int off = 32; off; off >>= 1) cnt += __shfl_xor(cnt, off);
    if (lane == 0) sred[wave] = (float)cnt;

    // stage Q tile into Pb[0] region (8192 elems, 16/thread)
    for (int i = 0; i < 2; ++i) {
        int e = tid + i * 512;
        int r = e >> 3, c = (e & 7) * 8;
        *(short8*)&PbB[r * 72 + c] = *(const short8*)&q[(bh + q0 + r) * HD + c];
    }
    __syncthreads();

    const float nmask = sred[0] + sred[1] + sred[2] + sred[3] +
                        sred[4] + sred[5] + sred[6] + sred[7];

    // Q as B-operand frags for this wave's 32 queries (2 x 16)
    short8 bq_[2][2];
    for (int mi = 0; mi < 2; ++mi) {
        bq_[mi][0] = *(const short8*)&PbB[(qoff + mi * 16 + lr) * 72 + lg * 8];
        bq_[mi][1] = *(const short8*)&PbB[(qoff + mi * 16 + lr) * 72 + 32 + lg * 8];
    }

    short8 ones;
    for (int j = 0; j < 8; ++j) ones[j] = (short)0x3F80;   // bf16 1.0

    f32x4 o[2][4], lacc[2];
    for (int mi = 0; mi < 2; ++mi) {
        lacc[mi] = (f32x4){0.f,0.f,0.f,0.f};
        for (int db = 0; db < 4; ++db) o[mi][db] = (f32x4){0.f,0.f,0.f,0.f};
    }

    // staging: 512 threads x 2 chunks cover both groups' K and V tiles
    short8 pk_[2], pv_[2];
    auto ld = [&](int it) {
        int k0 = it * 64;
        for (int i = 0; i < 2; ++i) {
            int e = tid + i * 512;
            int gg = e >> 9, r = (e >> 3) & 63, c = (e & 7) * 8;
            int kk = k0 + gg * 1024;
            pk_[i] = *(const short8*)&k [(bh + kk + r) * HD + c];
            pv_[i] = *(const short8*)&vt[(bhd + r) * SEQ + kk + c];
        }
    };
    ld(0);

    for (int it = 0; it < 16; ++it) {
        for (int i = 0; i < 2; ++i) {
            int e = tid + i * 512;
            int gg = e >> 9, r = (e >> 3) & 63, c = (e & 7) * 8;
            *(short8*)&KsB[(gg * 64 + r) * 72 + c] = pk_[i];
            *(short8*)&VtB[(gg * 64 + r) * 72 + c] = pv_[i];
        }
        __syncthreads();
        if (it + 1 < 16) ld(it + 1);

        // S^T = K Q^T over this group's 64-key tile
        for (int cb = 0; cb < 4; ++cb) {
            short8 a0 = *(const short8*)&KsB[(g * 64 + cb * 16 + lr) * 72 + lg * 8];
            short8 a1 = *(const short8*)&KsB[(g * 64 + cb * 16 + lr) * 72 + 32 + lg * 8];
            for (int mi = 0; mi < 2; ++mi) {
                f32x4 cc = (f32x4){0.f,0.f,0.f,0.f};
                cc = __builtin_amdgcn_mfma_f32_16x16x32_bf16(a0, bq_[mi][0], cc, 0, 0, 0);
                cc = __builtin_amdgcn_mfma_f32_16x16x32_bf16(a1, bq_[mi][1], cc, 0, 0, 0);
                uint2v pkv = {
                    cvt_pk_bf16(__builtin_amdgcn_exp2f(cc[0]),
                                __builtin_amdgcn_exp2f(cc[1])),
                    cvt_pk_bf16(__builtin_amdgcn_exp2f(cc[2]),
                                __builtin_amdgcn_exp2f(cc[3])) };
                *(uint2v*)&PbB[(g * 128 + qoff + mi * 16 + lr) * 72 + cb * 16 + lg * 4] = pkv;
            }
        }

        // O += P V ; l += P 1   (wave-private P rows: no barrier needed)
        short8 ap[2][2];
        for (int mi = 0; mi < 2; ++mi) {
            ap[mi][0] = *(const short8*)&PbB[(g * 128 + qoff + mi * 16 + lr) * 72 + lg * 8];
            ap[mi][1] = *(const short8*)&PbB[(g * 128 + qoff + mi * 16 + lr) * 72 + 32 + lg * 8];
        }
        for (int db = 0; db < 4; ++db) {
            short8 bv0 = *(const short8*)&VtB[(g * 64 + db * 16 + lr) * 72 + lg * 8];
            short8 bv1 = *(const short8*)&VtB[(g * 64 + db * 16 + lr) * 72 + 32 + lg * 8];
            for (int mi = 0; mi < 2; ++mi) {
                o[mi][db] = __builtin_amdgcn_mfma_f32_16x16x32_bf16(ap[mi][0], bv0, o[mi][db], 0, 0, 0);
                o[mi][db] = __builtin_amdgcn_mfma_f32_16x16x32_bf16(ap[mi][1], bv1, o[mi][db], 0, 0, 0);
            }
        }
        for (int mi = 0; mi < 2; ++mi) {
            lacc[mi] = __builtin_amdgcn_mfma_f32_16x16x32_bf16(ap[mi][0], ones, lacc[mi], 0, 0, 0);
            lacc[mi] = __builtin_amdgcn_mfma_f32_16x16x32_bf16(ap[mi][1], ones, lacc[mi], 0, 0, 0);
        }
        __syncthreads();
    }

    // combine the two key-halves through LDS scratch, normalize, store
    float* Osc  = (float*)(smem + 36864);  // 32 KB over Ks+Vt
    float* larr = (float*)smem;            // over Pb[0]
    if (g == 1) {
        for (int mi = 0; mi < 2; ++mi) {
            for (int db = 0; db < 4; ++db)
                for (int r = 0; r < 4; ++r)
                    Osc[(qoff + mi * 16 + lg * 4 + r) * 64 + db * 16 + lr] = o[mi][db][r];
            if (lr == 0)
                for (int r = 0; r < 4; ++r)
                    larr[qoff + mi * 16 + lg * 4 + r] = lacc[mi][r];
        }
    }
    __syncthreads();
    if (g == 0) {
        for (int mi = 0; mi < 2; ++mi) {
            int qr = qoff + mi * 16 + lg * 4;
            f32x4 linv;
            for (int r = 0; r < 4; ++r)
                linv[r] = 1.f / (lacc[mi][r] + larr[qr + r] - nmask);
            for (int db = 0; db < 4; ++db) {
                int col = h * HD + db * 16 + lr;
                float vv[4];
                for (int r = 0; r < 4; ++r)
                    vv[r] = (o[mi][db][r] + Osc[(qr + r) * 64 + db * 16 + lr]) * linv[r];
                bf16* p = attn + ((size_t)b * SEQ + q0 + qr) * EMB + col;
                st_bf2(p,           p + EMB,     vv[0], vv[1]);
                st_bf2(p + 2 * EMB, p + 3 * EMB, vv[2], vv[3]);
            }
        }
    }
}

// ---------------------------------------------------------------------------
extern "C" void kernel_launch(void* const* d_in, const int* in_sizes, int n_in,
                              void* d_out, int out_size, void* d_ws, size_t ws_size,
                              hipStream_t stream)
{
    const float* x    = (const float*)d_in[0];
    const int*   mask = (const int*)d_in[1];
    const float* Wq   = (const float*)d_in[2];
    const float* bq   = (const float*)d_in[3];
    const float* Wk   = (const float*)d_in[4];
    const float* bk   = (const float*)d_in[5];
    const float* Wv   = (const float*)d_in[6];
    const float* bv   = (const float*)d_in[7];
    const float* Wo   = (const float*)d_in[8];
    const float* bo   = (const float*)d_in[9];
    float* out = (float*)d_out;

    const size_t TENS = (size_t)BATCH * SEQ * EMB;   // 2^22
    bf16* q    = (bf16*)d_ws;
    bf16* kt   = q    + TENS;
    bf16* vt   = kt   + TENS;
    bf16* attn = vt   + TENS;
    bf16* xb   = attn + TENS;
    bf16* wb   = xb   + TENS;     // 4 x 2^20 = TENS

    cvt_pack<<<8192, 256, 0, stream>>>(x, Wq, Wk, Wv, Wo, (short*)xb);

    gemm_qkv2<<<dim3(24, 32), 256, 0, stream>>>(xb, wb, bq, bk, bv, mask, q, kt, vt);

    attn_flash11<<<dim3(SEQ / 128, NH, BATCH), 512, 0, stream>>>(q, kt, vt, mask, attn);

    gemm_out2<<<dim3(16, 32), 256, 0, stream>>>(attn, wb + ((size_t)3 << 20), bo, out);
}